// Round 1
// baseline (467.308 us; speedup 1.0000x reference)
//
#include <hip/hip_runtime.h>

// Problem geometry (fixed by setup_inputs): B=8, C=32, H=512, W=512, k=8.
// Output[b,c,h,w] = 0.8*x[b,c,h,w] + 0.2 * mean over valid neighbor blocks
// (dr,dc in {-1,0,1}^2 minus center) of x[b,c, h+dr*8, w+dc*8].
// Block grid is 64x64; neighbor count = rv*cv-1 where rv/cv = valid row/col
// block counts (2 at borders, 3 interior).

#define H 512
#define W 512
#define GROUPS_PER_ROW 128   // W/4
#define GROUPS_PER_PLANE 65536  // H * GROUPS_PER_ROW
#define PLANE_ELEMS 262144   // H*W

__global__ __launch_bounds__(256) void contam_kernel(const float* __restrict__ x,
                                                     float* __restrict__ out) {
    const int idx = blockIdx.x * blockDim.x + threadIdx.x;  // one float4 group
    const int plane  = idx >> 16;            // idx / GROUPS_PER_PLANE
    const int within = idx & (GROUPS_PER_PLANE - 1);
    const int h  = within >> 7;              // / GROUPS_PER_ROW
    const int w0 = (within & (GROUPS_PER_ROW - 1)) << 2;

    const float4* __restrict__ p4 =
        reinterpret_cast<const float4*>(x + (size_t)plane * PLANE_ELEMS);
    float4* __restrict__ o4 =
        reinterpret_cast<float4*>(out + (size_t)plane * PLANE_ELEMS);

    const bool up = (h  >= 8), dn = (h  < H - 8);
    const bool lf = (w0 >= 8), rt = (w0 < W - 8);

    const int g = h * GROUPS_PER_ROW + (w0 >> 2);

    float4 center = p4[g];
    float sx = 0.f, sy = 0.f, sz = 0.f, sw = 0.f;

#define ACC(gi) { float4 v = p4[(gi)]; sx += v.x; sy += v.y; sz += v.z; sw += v.w; }
    if (up) {
        const int gu = g - 8 * GROUPS_PER_ROW;
        if (lf) ACC(gu - 2);
        ACC(gu);
        if (rt) ACC(gu + 2);
    }
    if (lf) ACC(g - 2);
    if (rt) ACC(g + 2);
    if (dn) {
        const int gd = g + 8 * GROUPS_PER_ROW;
        if (lf) ACC(gd - 2);
        ACC(gd);
        if (rt) ACC(gd + 2);
    }
#undef ACC

    const int rv = 1 + (int)up + (int)dn;
    const int cv = 1 + (int)lf + (int)rt;
    const float inv = 0.2f / (float)(rv * cv - 1);

    float4 o;
    o.x = center.x * 0.8f + sx * inv;
    o.y = center.y * 0.8f + sy * inv;
    o.z = center.z * 0.8f + sz * inv;
    o.w = center.w * 0.8f + sw * inv;
    o4[g] = o;
}

extern "C" void kernel_launch(void* const* d_in, const int* in_sizes, int n_in,
                              void* d_out, int out_size, void* d_ws, size_t ws_size,
                              hipStream_t stream) {
    const float* x = (const float*)d_in[0];
    float* out = (float*)d_out;
    // total float4 groups: B*C * GROUPS_PER_PLANE = 256 * 65536 = 16,777,216
    const int total_groups = 256 * GROUPS_PER_PLANE;
    const int block = 256;
    const int grid = total_groups / block;  // 65536
    contam_kernel<<<grid, block, 0, stream>>>(x, out);
}